// Round 13
// baseline (146.129 us; speedup 1.0000x reference)
//
#include <hip/hip_runtime.h>
#include <math.h>

#define Bn 16
#define Cn 64
#define Hn 192
#define Wn 192
#define TH 16
#define TW 16
#define NPIX (Bn * Cn * Hn * Wn)       // 37748736
#define NTILE (Bn * (Hn / TH) * (Wn / TW))  // 2304
#define NBLKS 256
#define TPB (NTILE / NBLKS)            // 9 tiles per persistent block
#define XW_BYTES (18 * 18 * 128)       // 41472

typedef short bf16x8 __attribute__((ext_vector_type(8)));
typedef float f32x4 __attribute__((ext_vector_type(4)));
typedef __attribute__((address_space(1))) const unsigned int as1_u32;
typedef __attribute__((address_space(3))) unsigned int as3_u32;

// g_Ms[9 slices][64 rows][64 c] bf16; within a row, c-octet g stored at slot (g ^ (row&7)).
__device__ __align__(16) unsigned short g_Ms[9 * 64 * 64];
__device__ __align__(16) float g_b2[64];

static __device__ __forceinline__ unsigned short f2bf(float f) {
    union { float f; unsigned u; } x; x.f = f;
    unsigned r = x.u + 0x7fffu + ((x.u >> 16) & 1u);   // RNE
    return (unsigned short)(r >> 16);
}

__global__ void acdc_precompute(const float* __restrict__ cw, const float* __restrict__ A,
                                const float* __restrict__ D, const float* __restrict__ bias,
                                const int* __restrict__ perm) {
    __shared__ float mre[64];
    int p = blockIdx.x;
    int t = threadIdx.x;
    if (t < 64) {
        float re = 0.f;
        for (int k = 0; k < 64; ++k) {
            int a = (k * t) & 63;
            re += D[k] * cosf((float)a * 0.0981747704246810387f);  // pi/32
        }
        mre[t] = re;
    }
    __syncthreads();
    int pp = perm[p];
    for (int k0 = t; k0 < 576; k0 += 256) {
        int sp = k0 >> 6, c = k0 & 63;
        int g = c >> 3, cil = c & 7;
        float val = 0.f;
        for (int o = 0; o < 8; ++o) {
            int oc = g * 8 + o;
            float gco = mre[(pp - oc + 64) & 63] * A[oc] * (0.125f / 64.0f);
            val += gco * cw[(oc * 8 + cil) * 9 + sp];
        }
        g_Ms[((sp * 64 + p) << 6) + (((g ^ (p & 7)) << 3) | cil)] = f2bf(val);
    }
    if (p == 0 && t < 64)
        g_b2[t] = bias[perm[t]] * 0.125f;
}

// Persistent block: 1024 threads (16 waves), 1 block/CU (LDS 113.4 KB).
// M staged ONCE; per tile: async x-stage (T14) + barrier-free unrolled sp-loop.
__global__ __launch_bounds__(1024)
void acdc_main(const float* __restrict__ x, float* __restrict__ out) {
    __shared__ __align__(16) unsigned short Mlds[9 * 64 * 64];   // 73728 B
    __shared__ __align__(16) unsigned char xsb[XW_BYTES];        // 41472 B

    int tid = threadIdx.x;
    int lane = tid & 63, wv = tid >> 6;
    int b = blockIdx.x;

    // ---- stage M once: 72 x 1KB chunks via global_load_lds ----
    #pragma unroll
    for (int k = 0; k < 5; ++k) {
        int chunk = wv + k * 16;
        if (chunk < 72) {
            const unsigned char* src = (const unsigned char*)g_Ms + chunk * 1024 + lane * 16;
            __builtin_amdgcn_global_load_lds((as1_u32*)(const void*)src,
                (as3_u32*)(void*)((unsigned char*)Mlds + chunk * 1024), 16, 0, 0);
        }
    }

    int pxw = lane & 15, q = lane >> 4, rlane = lane & 15;

    // tile decode helper values (computed per tile)
    int bb = 0, h0 = 0, w0 = 0; bool edge = false;
    auto decode = [&](int t) {
        int id = b * TPB + t;
        int bw = id % 12, bh = (id / 12) % 12;
        bb = id / 144;
        h0 = bh * TH; w0 = bw * TW;
        edge = (bh == 0) | (bh == 11) | (bw == 0) | (bw == 11);
    };

    // ---- x stage: load phase (to regs) and write phase (cvt + ds_write) ----
    float4 va[4], vb[4];
    auto xload = [&](int t) {
        decode(t);
        const float* xb = x + (size_t)bb * Cn * Hn * Wn;
        #pragma unroll
        for (int k = 0; k < 4; ++k) {
            int idx = tid + (k << 10);
            if (idx >= 3456) break;
            int f = idx % 6;
            int rr = (idx / 6) % 18;
            int cp = idx / 108;
            int gh = h0 + rr - 1;
            int gwf = w0 + f * 4 - 4;
            const float* row0 = xb + ((size_t)(cp * 2) * Hn + gh) * Wn;
            const float* row1 = row0 + (size_t)(Hn * Wn);
            if (!edge) {
                va[k] = *(const float4*)(row0 + gwf);
                vb[k] = *(const float4*)(row1 + gwf);
            } else {
                bool ghok = (unsigned)gh < (unsigned)Hn;
                if (ghok && gwf >= 0 && gwf <= Wn - 4) {
                    va[k] = *(const float4*)(row0 + gwf);
                    vb[k] = *(const float4*)(row1 + gwf);
                } else {
                    float t0[4], t1[4];
                    #pragma unroll
                    for (int j = 0; j < 4; ++j) {
                        int gw = gwf + j;
                        bool ok = ghok && (unsigned)gw < (unsigned)Wn;
                        t0[j] = ok ? row0[gw] : 0.f;
                        t1[j] = ok ? row1[gw] : 0.f;
                    }
                    va[k] = (float4){t0[0], t0[1], t0[2], t0[3]};
                    vb[k] = (float4){t1[0], t1[1], t1[2], t1[3]};
                }
            }
        }
    };
    auto xwrite = [&]() {
        #pragma unroll
        for (int k = 0; k < 4; ++k) {
            int idx = tid + (k << 10);
            if (idx >= 3456) break;
            int f = idx % 6;
            int rr = (idx / 6) % 18;
            int cp = idx / 108;
            int chunk = cp >> 2;
            int sub = (cp & 3) * 4;
            float v0[4] = {va[k].x, va[k].y, va[k].z, va[k].w};
            float v1[4] = {vb[k].x, vb[k].y, vb[k].z, vb[k].w};
            #pragma unroll
            for (int j = 0; j < 4; ++j) {
                int col = f * 4 + j - 3;
                if ((unsigned)col >= 18u) continue;
                unsigned u;
                asm("v_cvt_pk_bf16_f32 %0, %1, %2" : "=v"(u) : "v"(v0[j]), "v"(v1[j]));
                int byte = (rr * 18 + col) * 128 + ((chunk ^ ((col + 3 * rr) & 7)) * 16) + sub;
                *(unsigned*)(xsb + byte) = u;
            }
        }
    };

    xload(0);
    xwrite();
    __syncthreads();   // publishes M + x(0)

    for (int t = 0; t < TPB; ++t) {
        decode(t);                       // current tile coords (for epilogue)
        int cbb = bb, ch0 = h0, cw0 = w0;
        if (t + 1 < TPB) xload(t + 1);   // issue next tile's loads; hide under compute

        // ---- compute tile t: barrier-free, fully unrolled ----
        f32x4 acc[4];
        #pragma unroll
        for (int m = 0; m < 4; ++m) acc[m] = (f32x4){0.f, 0.f, 0.f, 0.f};

        #pragma unroll
        for (int sp = 0; sp < 9; ++sp) {
            const int dy = sp / 3, dx = sp % 3;
            int col = pxw + dx;
            int row = wv + dy;
            int bbase = (row * 18 + col) * 128;
            int bswz = (col + 3 * row) & 7;
            #pragma unroll
            for (int kh = 0; kh < 2; ++kh) {
                int ksl = kh * 4 + q;
                bf16x8 bfr = *(const bf16x8*)(xsb + bbase + ((ksl ^ bswz) << 4));
                const unsigned char* mrow = (const unsigned char*)Mlds + sp * 8192 +
                                            rlane * 128 + ((ksl ^ (rlane & 7)) << 4);
                __builtin_amdgcn_s_setprio(1);
                #pragma unroll
                for (int m = 0; m < 4; ++m) {
                    bf16x8 am = *(const bf16x8*)(mrow + m * 2048);
                    acc[m] = __builtin_amdgcn_mfma_f32_16x16x32_bf16(am, bfr, acc[m], 0, 0, 0);
                }
                __builtin_amdgcn_s_setprio(0);
            }
        }

        // ---- epilogue: +bias, real-only stores (wave wv owns output row h0+wv) ----
        #pragma unroll
        for (int m = 0; m < 4; ++m) {
            int rbase = m * 16 + q * 4;
            float4 bq = *(const float4*)(g_b2 + rbase);
            float* orow = out + (((size_t)(cbb * Cn + rbase)) * Hn + (ch0 + wv)) * Wn + cw0 + pxw;
            orow[0]                      = acc[m][0] + bq.x;
            orow[(size_t)Hn * Wn]        = acc[m][1] + bq.y;
            orow[(size_t)2 * Hn * Wn]    = acc[m][2] + bq.z;
            orow[(size_t)3 * Hn * Wn]    = acc[m][3] + bq.w;
        }

        __syncthreads();                 // all xsb reads for tile t done
        if (t + 1 < TPB) {
            xwrite();                    // cvt + ds_write next tile
        }
        __syncthreads();                 // publish x(t+1)
    }
}

extern "C" void kernel_launch(void* const* d_in, const int* in_sizes, int n_in,
                              void* d_out, int out_size, void* d_ws, size_t ws_size,
                              hipStream_t stream) {
    const float* x    = (const float*)d_in[0];
    const float* cw   = (const float*)d_in[1];
    const float* A    = (const float*)d_in[2];
    const float* D    = (const float*)d_in[3];
    const float* bias = (const float*)d_in[4];
    const int*   perm = (const int*)d_in[5];

    acdc_precompute<<<dim3(64), dim3(256), 0, stream>>>(cw, A, D, bias, perm);
    acdc_main<<<dim3(NBLKS), dim3(1024), 0, stream>>>(x, (float*)d_out);
}

// Round 14
// 119.385 us; speedup vs baseline: 1.2240x; 1.2240x over previous
//
#include <hip/hip_runtime.h>
#include <math.h>

#define Bn 16
#define Cn 64
#define Hn 192
#define Wn 192
#define TH 16
#define TW 16
#define NPIX (Bn * Cn * Hn * Wn)       // 37748736
#define NBLKS 256
#define TPB 9                          // 3x3 tile patch per persistent block
#define XW_BYTES (18 * 18 * 128)       // 41472

typedef short bf16x8 __attribute__((ext_vector_type(8)));
typedef float f32x4 __attribute__((ext_vector_type(4)));
typedef __attribute__((address_space(1))) const unsigned int as1_u32;
typedef __attribute__((address_space(3))) unsigned int as3_u32;

// g_Ms[9 slices][64 rows][64 c] bf16; within a row, c-octet g stored at slot (g ^ (row&7)).
__device__ __align__(16) unsigned short g_Ms[9 * 64 * 64];
__device__ __align__(16) float g_b2[64];

static __device__ __forceinline__ unsigned short f2bf(float f) {
    union { float f; unsigned u; } x; x.f = f;
    unsigned r = x.u + 0x7fffu + ((x.u >> 16) & 1u);   // RNE
    return (unsigned short)(r >> 16);
}

__global__ void acdc_precompute(const float* __restrict__ cw, const float* __restrict__ A,
                                const float* __restrict__ D, const float* __restrict__ bias,
                                const int* __restrict__ perm) {
    __shared__ float mre[64];
    int p = blockIdx.x;
    int t = threadIdx.x;
    if (t < 64) {
        float re = 0.f;
        for (int k = 0; k < 64; ++k) {
            int a = (k * t) & 63;
            re += D[k] * cosf((float)a * 0.0981747704246810387f);  // pi/32
        }
        mre[t] = re;
    }
    __syncthreads();
    int pp = perm[p];
    for (int k0 = t; k0 < 576; k0 += 256) {
        int sp = k0 >> 6, c = k0 & 63;
        int g = c >> 3, cil = c & 7;
        float val = 0.f;
        for (int o = 0; o < 8; ++o) {
            int oc = g * 8 + o;
            float gco = mre[(pp - oc + 64) & 63] * A[oc] * (0.125f / 64.0f);
            val += gco * cw[(oc * 8 + cil) * 9 + sp];
        }
        g_Ms[((sp * 64 + p) << 6) + (((g ^ (p & 7)) << 3) | cil)] = f2bf(val);
    }
    if (p == 0 && t < 64)
        g_b2[t] = bias[perm[t]] * 0.125f;
}

// Persistent block: 1024 threads, 1 block/CU (LDS 115 KB). M staged ONCE.
// Block owns a 3x3 SPATIAL PATCH of tiles (intra-block halo reuse) + XCD swizzle
// (inter-block halo reuse) — fixes R13's 4.3x FETCH regression.
__global__ __launch_bounds__(1024)
void acdc_main(const float* __restrict__ x, float* __restrict__ out) {
    __shared__ __align__(16) unsigned short Mlds[9 * 64 * 64];   // 73728 B
    __shared__ __align__(16) unsigned char xsb[XW_BYTES];        // 41472 B

    int tid = threadIdx.x;
    int lane = tid & 63, wv = tid >> 6;
    // bijective XCD swizzle: XCD x gets logical blocks [x*32, x*32+32) = 2 whole batches
    int Lb = (blockIdx.x & 7) * (NBLKS / 8) + (blockIdx.x >> 3);
    int pid = Lb & 15, batch = Lb >> 4;
    int pr = pid >> 2, pc = pid & 3;     // patch coords in 4x4 grid

    // ---- stage M once: 72 x 1KB chunks via global_load_lds ----
    #pragma unroll
    for (int k = 0; k < 5; ++k) {
        int chunk = wv + k * 16;
        if (chunk < 72) {
            const unsigned char* src = (const unsigned char*)g_Ms + chunk * 1024 + lane * 16;
            __builtin_amdgcn_global_load_lds((as1_u32*)(const void*)src,
                (as3_u32*)(void*)((unsigned char*)Mlds + chunk * 1024), 16, 0, 0);
        }
    }

    int pxw = lane & 15, q = lane >> 4, rlane = lane & 15;

    int bb = batch, h0 = 0, w0 = 0; bool edge = false;
    auto decode = [&](int t) {
        int bh = pr * 3 + t / 3, bw = pc * 3 + t % 3;
        h0 = bh * TH; w0 = bw * TW;
        edge = (bh == 0) | (bh == 11) | (bw == 0) | (bw == 11);
    };

    // ---- x stage: load phase (to regs) and write phase (cvt + ds_write) ----
    float4 va[4], vb[4];
    auto xload = [&](int t) {
        decode(t);
        const float* xb = x + (size_t)bb * Cn * Hn * Wn;
        #pragma unroll
        for (int k = 0; k < 4; ++k) {
            int idx = tid + (k << 10);
            if (idx >= 3456) break;
            int f = idx % 6;
            int rr = (idx / 6) % 18;
            int cp = idx / 108;
            int gh = h0 + rr - 1;
            int gwf = w0 + f * 4 - 4;
            const float* row0 = xb + ((size_t)(cp * 2) * Hn + gh) * Wn;
            const float* row1 = row0 + (size_t)(Hn * Wn);
            if (!edge) {
                va[k] = *(const float4*)(row0 + gwf);
                vb[k] = *(const float4*)(row1 + gwf);
            } else {
                bool ghok = (unsigned)gh < (unsigned)Hn;
                if (ghok && gwf >= 0 && gwf <= Wn - 4) {
                    va[k] = *(const float4*)(row0 + gwf);
                    vb[k] = *(const float4*)(row1 + gwf);
                } else {
                    float t0[4], t1[4];
                    #pragma unroll
                    for (int j = 0; j < 4; ++j) {
                        int gw = gwf + j;
                        bool ok = ghok && (unsigned)gw < (unsigned)Wn;
                        t0[j] = ok ? row0[gw] : 0.f;
                        t1[j] = ok ? row1[gw] : 0.f;
                    }
                    va[k] = (float4){t0[0], t0[1], t0[2], t0[3]};
                    vb[k] = (float4){t1[0], t1[1], t1[2], t1[3]};
                }
            }
        }
    };
    auto xwrite = [&]() {
        #pragma unroll
        for (int k = 0; k < 4; ++k) {
            int idx = tid + (k << 10);
            if (idx >= 3456) break;
            int f = idx % 6;
            int rr = (idx / 6) % 18;
            int cp = idx / 108;
            int chunk = cp >> 2;
            int sub = (cp & 3) * 4;
            float v0[4] = {va[k].x, va[k].y, va[k].z, va[k].w};
            float v1[4] = {vb[k].x, vb[k].y, vb[k].z, vb[k].w};
            #pragma unroll
            for (int j = 0; j < 4; ++j) {
                int col = f * 4 + j - 3;
                if ((unsigned)col >= 18u) continue;
                unsigned u;
                asm("v_cvt_pk_bf16_f32 %0, %1, %2" : "=v"(u) : "v"(v0[j]), "v"(v1[j]));
                int byte = (rr * 18 + col) * 128 + ((chunk ^ ((col + 3 * rr) & 7)) * 16) + sub;
                *(unsigned*)(xsb + byte) = u;
            }
        }
    };

    xload(0);
    xwrite();
    __syncthreads();   // publishes M + x(0)

    for (int t = 0; t < TPB; ++t) {
        decode(t);
        int ch0 = h0, cw0 = w0;
        if (t + 1 < TPB) xload(t + 1);   // issue next tile's loads; hide under compute

        // ---- compute tile t: barrier-free, fully unrolled ----
        f32x4 acc[4];
        #pragma unroll
        for (int m = 0; m < 4; ++m) acc[m] = (f32x4){0.f, 0.f, 0.f, 0.f};

        #pragma unroll
        for (int sp = 0; sp < 9; ++sp) {
            const int dy = sp / 3, dx = sp % 3;
            int col = pxw + dx;
            int row = wv + dy;
            int bbase = (row * 18 + col) * 128;
            int bswz = (col + 3 * row) & 7;
            #pragma unroll
            for (int kh = 0; kh < 2; ++kh) {
                int ksl = kh * 4 + q;
                bf16x8 bfr = *(const bf16x8*)(xsb + bbase + ((ksl ^ bswz) << 4));
                const unsigned char* mrow = (const unsigned char*)Mlds + sp * 8192 +
                                            rlane * 128 + ((ksl ^ (rlane & 7)) << 4);
                __builtin_amdgcn_s_setprio(1);
                #pragma unroll
                for (int m = 0; m < 4; ++m) {
                    bf16x8 am = *(const bf16x8*)(mrow + m * 2048);
                    acc[m] = __builtin_amdgcn_mfma_f32_16x16x32_bf16(am, bfr, acc[m], 0, 0, 0);
                }
                __builtin_amdgcn_s_setprio(0);
            }
        }

        // ---- epilogue: +bias, real-only stores (wave wv owns output row ch0+wv) ----
        #pragma unroll
        for (int m = 0; m < 4; ++m) {
            int rbase = m * 16 + q * 4;
            float4 bq = *(const float4*)(g_b2 + rbase);
            float* orow = out + (((size_t)(bb * Cn + rbase)) * Hn + (ch0 + wv)) * Wn + cw0 + pxw;
            orow[0]                      = acc[m][0] + bq.x;
            orow[(size_t)Hn * Wn]        = acc[m][1] + bq.y;
            orow[(size_t)2 * Hn * Wn]    = acc[m][2] + bq.z;
            orow[(size_t)3 * Hn * Wn]    = acc[m][3] + bq.w;
        }

        __syncthreads();                 // all xsb reads for tile t done
        if (t + 1 < TPB) {
            xwrite();                    // cvt + ds_write next tile
        }
        __syncthreads();                 // publish x(t+1)
    }
}

extern "C" void kernel_launch(void* const* d_in, const int* in_sizes, int n_in,
                              void* d_out, int out_size, void* d_ws, size_t ws_size,
                              hipStream_t stream) {
    const float* x    = (const float*)d_in[0];
    const float* cw   = (const float*)d_in[1];
    const float* A    = (const float*)d_in[2];
    const float* D    = (const float*)d_in[3];
    const float* bias = (const float*)d_in[4];
    const int*   perm = (const int*)d_in[5];

    acdc_precompute<<<dim3(64), dim3(256), 0, stream>>>(cw, A, D, bias, perm);
    acdc_main<<<dim3(NBLKS), dim3(1024), 0, stream>>>(x, (float*)d_out);
}